// Round 11
// baseline (116.880 us; speedup 1.0000x reference)
//
#include <hip/hip_runtime.h>
#include <hip/hip_bf16.h>

// Problem constants
#define B_    4
#define T_    4096
#define D_    1024
#define NH_   16
#define NS_   64
#define HD_   64
#define ALPHA_ 0.1f
#define M_    (B_*T_)        // 16384 rows
#define N_    (NH_*NS_)      // 1024 cols (head*slot)
#define NCH_  128            // time chunks for the suffix scan
#define CHUNK_ (T_/NCH_)     // 32

typedef __attribute__((ext_vector_type(8))) short short8v;
typedef __attribute__((ext_vector_type(4))) float f32x4;
typedef _Float16 f16x8 __attribute__((ext_vector_type(8)));

__device__ inline unsigned short f2bf(float x) {
    unsigned u = __float_as_uint(x);
    unsigned r = u + 0x7FFF + ((u >> 16) & 1);   // RNE
    return (unsigned short)(r >> 16);
}

// ---------------------------------------------------------------------------
// Kernel 0 (merged): blocks [0,2048) = H fp32->bf16; [2048,2304) = protoproj;
// [2304,2560) = zero d_out. protoproj + zeroing hide under h2bf's HBM BW.
__global__ __launch_bounds__(256)
void k_prep(const float* __restrict__ H, unsigned short* __restrict__ Hb,
            const float* __restrict__ proto, const float* __restrict__ W,
            unsigned short* __restrict__ Pb, float* __restrict__ outp) {
    __shared__ float pl[64][68];
    __shared__ float Wl[64][68];
    int bid = blockIdx.x;
    int tid = threadIdx.x;
    if (bid < 2048) {
        // ---- h2bf ----
        int idx = bid * 256 + tid;                    // unit = 8 floats
        const int stride = 2048 * 256;
        #pragma unroll
        for (int it = 0; it < 4; ++it) {
            int e = (idx + it * stride) * 8;
            float4 f0 = *(const float4*)&H[e];
            float4 f1 = *(const float4*)&H[e + 4];
            __hip_bfloat162 q0 = __float22bfloat162_rn(make_float2(f0.x, f0.y));
            __hip_bfloat162 q1 = __float22bfloat162_rn(make_float2(f0.z, f0.w));
            __hip_bfloat162 q2 = __float22bfloat162_rn(make_float2(f1.x, f1.y));
            __hip_bfloat162 q3 = __float22bfloat162_rn(make_float2(f1.z, f1.w));
            uint4 u = {*(unsigned*)&q0, *(unsigned*)&q1,
                       *(unsigned*)&q2, *(unsigned*)&q3};
            *(uint4*)&Hb[e] = u;
        }
    } else if (bid < 2304) {
        // ---- protoproj: P[h*64+s][m] = (1/8) sum_k proto[s,h*64+k]*W[h*64+k,m]
        int bid2 = bid - 2048;
        int h = bid2 >> 4, mr = bid2 & 15;
        int m0 = mr * 64;
        int rr = tid >> 2, cg = (tid & 3) * 16;
        #pragma unroll
        for (int i = 0; i < 4; ++i)
            *(float4*)&pl[rr][cg + i * 4] =
                *(const float4*)&proto[rr * D_ + h * 64 + cg + i * 4];
        #pragma unroll
        for (int i = 0; i < 4; ++i)
            *(float4*)&Wl[rr][cg + i * 4] =
                *(const float4*)&W[(h * 64 + rr) * D_ + m0 + cg + i * 4];
        __syncthreads();
        int s = tid & 63, mg = (tid >> 6) * 16;
        float acc[16] = {};
        for (int k = 0; k < 64; ++k) {
            float pv = pl[s][k];
            #pragma unroll
            for (int i = 0; i < 16; ++i) acc[i] += pv * Wl[k][mg + i];
        }
        unsigned short ob[16];
        #pragma unroll
        for (int i = 0; i < 16; ++i) ob[i] = f2bf(0.125f * acc[i]);
        unsigned short* dst = &Pb[(size_t)(h * 64 + s) * D_ + m0 + mg];
        *(uint4*)dst       = *(uint4*)&ob[0];
        *(uint4*)(dst + 8) = *(uint4*)&ob[8];
    } else {
        // ---- zero d_out (262144 floats) ----
        int bid3 = bid - 2304;
        int off = bid3 * 1024 + tid * 4;
        *(float4*)&outp[off] = (float4){0.f, 0.f, 0.f, 0.f};
    }
}

// ---------------------------------------------------------------------------
// Kernel 2 (v4): pure bf16 MFMA GEMM -> raw scores in f16 (unchanged from R10:
// BK=64 single-buffered, both-sides T2 swizzle via pre-swizzled global src).
__global__ __launch_bounds__(256)
void k_gemm(const unsigned short* __restrict__ Ab,   // Hb [M_, D_] bf16
            const unsigned short* __restrict__ Bp,   // Pb [N_, D_] bf16
            _Float16* __restrict__ C) {              // scores [M_, N_] f16
    __shared__ unsigned short As[128 * 64];   // 16 KB
    __shared__ unsigned short Bs[128 * 64];   // 16 KB
    int tid = threadIdx.x;
    int bid = blockIdx.x;
    int wgid = (bid & 7) * 128 + (bid >> 3);
    int bm = wgid >> 3, bn = wgid & 7;
    int m0 = bm * 128, n0 = bn * 128;
    int l = tid & 63, wv = tid >> 6;
    int wr = wv >> 1, wc = wv & 1;
    int lr = l & 15, lk = l >> 4;

    int srow = tid >> 3;                  // 0..31
    int skgs = (tid & 7) ^ (srow & 7);    // pre-swizzled global 16B group
    const unsigned short* Ap = Ab + (size_t)(m0 + srow) * D_ + skgs * 8;
    const unsigned short* Bq = Bp + (size_t)(n0 + srow) * D_ + skgs * 8;

    f32x4 acc[4][4];
    #pragma unroll
    for (int i = 0; i < 4; ++i)
        #pragma unroll
        for (int j = 0; j < 4; ++j) acc[i][j] = (f32x4){0.f, 0.f, 0.f, 0.f};

    for (int k0 = 0; k0 < D_; k0 += 64) {
        __syncthreads();   // previous tile's MFMA reads complete
        #pragma unroll
        for (int i = 0; i < 4; ++i) {
            __builtin_amdgcn_global_load_lds(
                (const __attribute__((address_space(1))) void*)(Ap + (size_t)(i * 32) * D_ + k0),
                (__attribute__((address_space(3))) void*)(&As[tid * 8 + i * 2048]), 16, 0, 0);
            __builtin_amdgcn_global_load_lds(
                (const __attribute__((address_space(1))) void*)(Bq + (size_t)(i * 32) * D_ + k0),
                (__attribute__((address_space(3))) void*)(&Bs[tid * 8 + i * 2048]), 16, 0, 0);
        }
        __syncthreads();   // staging visible
        #pragma unroll
        for (int kk = 0; kk < 2; ++kk) {
            short8v af[4], bf[4];
            int gp = ((kk * 4 + lk) ^ (lr & 7)) * 8;
            #pragma unroll
            for (int m = 0; m < 4; ++m)
                af[m] = *(const short8v*)&As[(wr * 64 + m * 16 + lr) * 64 + gp];
            #pragma unroll
            for (int n = 0; n < 4; ++n)
                bf[n] = *(const short8v*)&Bs[(wc * 64 + n * 16 + lr) * 64 + gp];
            #pragma unroll
            for (int m = 0; m < 4; ++m)
                #pragma unroll
                for (int n = 0; n < 4; ++n)
                    acc[m][n] = __builtin_amdgcn_mfma_f32_16x16x32_bf16(
                        af[m], bf[n], acc[m][n], 0, 0, 0);
        }
    }

    int crow = m0 + wr * 64 + lk * 4;
    int ccol = n0 + wc * 64 + lr;
    #pragma unroll
    for (int m = 0; m < 4; ++m)
        #pragma unroll
        for (int n = 0; n < 4; ++n)
            #pragma unroll
            for (int j = 0; j < 4; ++j)
                C[(size_t)(crow + m * 16 + j) * N_ + ccol + n * 16] =
                    (_Float16)acc[m][n][j];
}

// ---------------------------------------------------------------------------
// Kernel 3 (v2): per-chunk g-products, vectorized (unchanged).
__global__ __launch_bounds__(256)
void k_cp(const _Float16* __restrict__ S, float* __restrict__ cp) {
    int bid = blockIdx.x;                 // 256
    int bh = bid >> 2, qt = bid & 3;
    int b = bh >> 4, h = bh & 15;
    int w = threadIdx.x >> 6, l = threadIdx.x & 63;
    int sg = (l & 7) * 8;
    for (int k = 0; k < 8; ++k) {
        int c = qt * 32 + w * 8 + k;
        int tb = c * CHUNK_;
        float pg[8] = {1.f, 1.f, 1.f, 1.f, 1.f, 1.f, 1.f, 1.f};
        #pragma unroll
        for (int i = 0; i < 4; ++i) {
            int t = tb + (l >> 3) + i * 8;
            f16x8 sv = *(const f16x8*)(S + (size_t)(b * T_ + t) * N_ + h * 64 + sg);
            float e[8]; float ps = 0.f;
            #pragma unroll
            for (int j = 0; j < 8; ++j) { e[j] = __expf((float)sv[j]); ps += e[j]; }
            ps += __shfl_xor(ps, 1);
            ps += __shfl_xor(ps, 2);
            ps += __shfl_xor(ps, 4);
            float inv = 1.f / ps;
            #pragma unroll
            for (int j = 0; j < 8; ++j) pg[j] *= 1.f - ALPHA_ * (e[j] * inv);
        }
        #pragma unroll
        for (int off = 8; off <= 32; off <<= 1)
            #pragma unroll
            for (int j = 0; j < 8; ++j) pg[j] *= __shfl_xor(pg[j], off);
        if ((l >> 3) == 0) {
            int base = (bh * NCH_ + c) * 64 + l * 8;
            *(float4*)&cp[base]     = (float4){pg[0], pg[1], pg[2], pg[3]};
            *(float4*)&cp[base + 4] = (float4){pg[4], pg[5], pg[6], pg[7]};
        }
    }
}

// ---------------------------------------------------------------------------
// Kernel 3b: PARALLEL cross-chunk exclusive suffix scan (unchanged).
__global__ __launch_bounds__(256)
void k_scan(const float* __restrict__ cp, float* __restrict__ csuf) {
    int bh = blockIdx.x;                  // 64
    __shared__ float buf[128][64];        // 32 KB
    __shared__ float segp[4][64];
    int tid = threadIdx.x;
    #pragma unroll
    for (int i = 0; i < 8; ++i) {
        int e = tid * 4 + i * 1024;
        int c = e >> 6, sc = e & 63;
        *(float4*)&buf[c][sc] = *(const float4*)&cp[(bh * NCH_ + c) * 64 + sc];
    }
    __syncthreads();
    int s = tid & 63, seg = tid >> 6;
    float pp = 1.f;
    #pragma unroll
    for (int r = 0; r < 32; ++r) pp *= buf[seg * 32 + r][s];
    segp[seg][s] = pp;
    __syncthreads();
    float suf = 1.f;
    if (seg <= 2) suf *= segp[3][s];
    if (seg <= 1) suf *= segp[2][s];
    if (seg == 0) suf *= segp[1][s];
    #pragma unroll
    for (int r = 31; r >= 0; --r) {
        int c = seg * 32 + r;
        csuf[(bh * NCH_ + c) * 64 + s] = suf;   // EXCLUSIVE suffix
        suf *= buf[c][s];
    }
}

// ---------------------------------------------------------------------------
// Kernel 4 (v4): softmax + weff walk + MFMA output accumulation.
// Change vs R10: grid 2048 (cf = 32 chunks of 128 t), 2 iters/block:
// halves the per-block serial barrier-chain, doubles scheduling granularity.
__global__ __launch_bounds__(256)
void k_out_mfma(const _Float16* __restrict__ S,       // raw scores
                const unsigned short* __restrict__ Hb,// bf16 H
                const float* __restrict__ csuf,
                float* __restrict__ out) {
    int bx = blockIdx.x;                  // 2048
    int cf = bx & 31, h = (bx >> 5) & 15, b = bx >> 9;
    __shared__ _Float16 ws16[64][72];           // softmaxed w
    __shared__ unsigned short tmp[64][72];      // staged Hb rows
    __shared__ float ppl[4][64];                // per-16-row g partial products
    __shared__ _Float16 wt[8 * 64 * 8];         // w_eff^T subtiled [tg][s][8]
    __shared__ _Float16 hd[8 * 64 * 8];         // H^T    subtiled [tg][d][8]
    int tid = threadIdx.x;
    int lr0 = tid >> 3, lc = (tid & 7) * 8;     // load role: rows lr0, lr0+32
    int s = tid & 63, q = tid >> 6;             // walk/transpose role
    int fr = s & 15, fk = s >> 4, wv = q;       // mfma role

    // T14: issue it=0 loads first so they overlap the csuf loads
    size_t rr0 = (size_t)(b * T_ + cf * 128 + lr0) * N_ + h * 64 + lc;
    f16x8  sv0 = *(const f16x8*)(S + rr0);
    f16x8  sv1 = *(const f16x8*)(S + rr0 + (size_t)32 * N_);
    short8v hv0 = *(const short8v*)(Hb + rr0);
    short8v hv1 = *(const short8v*)(Hb + rr0 + (size_t)32 * N_);

    // prologue: su[k] = exclusive suffix of chunk (cf*4 + k), k = 0..3
    int cbase = (b * NH_ + h) * NCH_ + cf * 4;
    float su[4];
    #pragma unroll
    for (int k = 0; k < 4; ++k)
        su[k] = csuf[(cbase + k) * 64 + s];

    f32x4 acc[4];
    #pragma unroll
    for (int n = 0; n < 4; ++n) acc[n] = (f32x4){0.f, 0.f, 0.f, 0.f};

    for (int it = 0; it < 2; ++it) {
        // softmax per row (8-lane group, no max-sub; |score| small)
        _Float16 w0[8], w1[8];
        {
            float e[8]; float ps = 0.f;
            #pragma unroll
            for (int j = 0; j < 8; ++j) { e[j] = __expf((float)sv0[j]); ps += e[j]; }
            ps += __shfl_xor(ps, 1); ps += __shfl_xor(ps, 2); ps += __shfl_xor(ps, 4);
            float inv = 1.f / ps;
            #pragma unroll
            for (int j = 0; j < 8; ++j) w0[j] = (_Float16)(e[j] * inv);
        }
        {
            float e[8]; float ps = 0.f;
            #pragma unroll
            for (int j = 0; j < 8; ++j) { e[j] = __expf((float)sv1[j]); ps += e[j]; }
            ps += __shfl_xor(ps, 1); ps += __shfl_xor(ps, 2); ps += __shfl_xor(ps, 4);
            float inv = 1.f / ps;
            #pragma unroll
            for (int j = 0; j < 8; ++j) w1[j] = (_Float16)(e[j] * inv);
        }
        // (barrier A removed: prior iter's barrier D already ordered all
        //  ws16/tmp readers; MFMA between D and here reads only wt/hd)
        *(f16x8*)&ws16[lr0][lc]      = *(f16x8*)w0;
        *(f16x8*)&ws16[lr0 + 32][lc] = *(f16x8*)w1;
        *(short8v*)&tmp[lr0][lc]      = hv0;
        *(short8v*)&tmp[lr0 + 32][lc] = hv1;
        __syncthreads();                  // B: ws16 + tmp visible
        // T14: issue next iteration's loads now (regs free, latency hidden)
        if (it < 1) {
            size_t rn = rr0 + (size_t)64 * N_;
            sv0 = *(const f16x8*)(S + rn);
            sv1 = *(const f16x8*)(S + rn + (size_t)32 * N_);
            hv0 = *(const short8v*)(Hb + rn);
            hv1 = *(const short8v*)(Hb + rn + (size_t)32 * N_);
        }
        // ppl: partial product of g over this thread's 16 rows
        {
            float pp = 1.f;
            #pragma unroll
            for (int r = 0; r < 16; ++r)
                pp *= 1.f - ALPHA_ * (float)ws16[q * 16 + r][s];
            ppl[q][s] = pp;
        }
        // transpose Hb: thread (q,s): tg = q and q+4, cvt bf16 -> f16
        #pragma unroll
        for (int x = 0; x < 2; ++x) {
            int tg = q + x * 4;
            _Float16 hreg[8];
            #pragma unroll
            for (int r = 0; r < 8; ++r) {
                unsigned short ub = tmp[tg * 8 + r][s];
                hreg[r] = (_Float16)__uint_as_float((unsigned)ub << 16);
            }
            *(f16x8*)&hd[(tg * 64 + s) * 8] = *(f16x8*)hreg;
        }
        __syncthreads();                  // C: ppl + hd visible
        // walk: rows q*16..q*16+15 backward; chunk split at q<2 | q>=2
        {
            float suf = (q >= 2) ? su[it * 2 + 1] : su[it * 2];
            if (q == 2) suf *= ppl[3][s];
            if (q == 0) suf *= ppl[1][s];
            _Float16 wr16[16];
            #pragma unroll
            for (int r = 15; r >= 0; --r) {
                float wv_ = (float)ws16[q * 16 + r][s];
                wr16[r] = (_Float16)(ALPHA_ * wv_ * suf);
                suf *= 1.f - ALPHA_ * wv_;
            }
            *(f16x8*)&wt[((2 * q)     * 64 + s) * 8] = *(f16x8*)&wr16[0];
            *(f16x8*)&wt[((2 * q + 1) * 64 + s) * 8] = *(f16x8*)&wr16[8];
        }
        __syncthreads();                  // D: wt visible
        // MFMA: wave wv -> s-block wv*16, all 64 d; K=64 = 2 k-steps
        #pragma unroll
        for (int kk = 0; kk < 2; ++kk) {
            int tg = kk * 4 + fk;
            f16x8 af = *(const f16x8*)&wt[(tg * 64 + wv * 16 + fr) * 8];
            #pragma unroll
            for (int n = 0; n < 4; ++n) {
                f16x8 bf = *(const f16x8*)&hd[(tg * 64 + n * 16 + fr) * 8];
                acc[n] = __builtin_amdgcn_mfma_f32_16x16x32_f16(
                    af, bf, acc[n], 0, 0, 0);
            }
        }
    }
    // D layout: row (s-dim) = fk*4 + j, col (d-dim) = fr
    #pragma unroll
    for (int n = 0; n < 4; ++n)
        #pragma unroll
        for (int j = 0; j < 4; ++j)
            atomicAdd(&out[((b * NS_ + wv * 16 + fk * 4 + j) * NH_ + h) * HD_
                           + n * 16 + fr],
                      acc[n][j]);
}

// ---------------------------------------------------------------------------
extern "C" void kernel_launch(void* const* d_in, const int* in_sizes, int n_in,
                              void* d_out, int out_size, void* d_ws, size_t ws_size,
                              hipStream_t stream) {
    const float* H     = (const float*)d_in[0];
    const float* proto = (const float*)d_in[1];
    const float* W     = (const float*)d_in[2];
    float* out = (float*)d_out;
    char*  ws  = (char*)d_ws;

    _Float16*       S  = (_Float16*)ws;                                  // 32 MB
    unsigned short* Hb = (unsigned short*)(ws + (size_t)M_ * N_ * 2);    // 32 MB
    unsigned short* Pb = (unsigned short*)(ws + (size_t)M_ * N_ * 2
                                              + (size_t)M_ * D_ * 2);    // 2 MB
    float* cp   = (float*)((char*)Pb + (size_t)N_ * D_ * 2);             // 2 MB
    float* csuf = cp + (size_t)B_ * NH_ * NCH_ * 64;                     // 2 MB

    k_prep      <<<2560,              256, 0, stream>>>(H, Hb, proto, W, Pb, out);
    k_gemm      <<<(M_/128)*(N_/128), 256, 0, stream>>>(Hb, Pb, S);
    k_cp        <<<256,               256, 0, stream>>>(S, cp);
    k_scan      <<<B_*NH_,            256, 0, stream>>>(cp, csuf);
    k_out_mfma  <<<B_*NH_*32,         256, 0, stream>>>(S, Hb, csuf, out);
}

// Round 12
// 110.602 us; speedup vs baseline: 1.0568x; 1.0568x over previous
//
#include <hip/hip_runtime.h>
#include <hip/hip_bf16.h>

// Problem constants
#define B_    4
#define T_    4096
#define D_    1024
#define NH_   16
#define NS_   64
#define HD_   64
#define ALPHA_ 0.1f
#define M_    (B_*T_)        // 16384 rows
#define N_    (NH_*NS_)      // 1024 cols (head*slot)
#define NCH_  128            // time chunks for the suffix scan
#define CHUNK_ (T_/NCH_)     // 32

typedef __attribute__((ext_vector_type(8))) short short8v;
typedef __attribute__((ext_vector_type(4))) float f32x4;
typedef _Float16 f16x8 __attribute__((ext_vector_type(8)));

__device__ inline unsigned short f2bf(float x) {
    unsigned u = __float_as_uint(x);
    unsigned r = u + 0x7FFF + ((u >> 16) & 1);   // RNE
    return (unsigned short)(r >> 16);
}

// ---------------------------------------------------------------------------
// Kernel 0 (v2): merged prep, ZERO LDS (lesson R11: merged kernels share the
// max LDS footprint — protoproj's 35 KB had halved h2bf's occupancy).
// blocks [0,256) = protoproj (direct L2 reads); [256,512) = zero d_out;
// [512,2560) = H fp32->bf16.
__global__ __launch_bounds__(256)
void k_prep(const float* __restrict__ H, unsigned short* __restrict__ Hb,
            const float* __restrict__ proto, const float* __restrict__ W,
            unsigned short* __restrict__ Pb, float* __restrict__ outp) {
    int bid = blockIdx.x;
    int tid = threadIdx.x;
    if (bid >= 512) {
        // ---- h2bf ----
        int idx = (bid - 512) * 256 + tid;            // unit = 8 floats
        const int stride = 2048 * 256;
        #pragma unroll
        for (int it = 0; it < 4; ++it) {
            int e = (idx + it * stride) * 8;
            float4 f0 = *(const float4*)&H[e];
            float4 f1 = *(const float4*)&H[e + 4];
            __hip_bfloat162 q0 = __float22bfloat162_rn(make_float2(f0.x, f0.y));
            __hip_bfloat162 q1 = __float22bfloat162_rn(make_float2(f0.z, f0.w));
            __hip_bfloat162 q2 = __float22bfloat162_rn(make_float2(f1.x, f1.y));
            __hip_bfloat162 q3 = __float22bfloat162_rn(make_float2(f1.z, f1.w));
            uint4 u = {*(unsigned*)&q0, *(unsigned*)&q1,
                       *(unsigned*)&q2, *(unsigned*)&q3};
            *(uint4*)&Hb[e] = u;
        }
    } else if (bid < 256) {
        // ---- protoproj (LDS-free): P[h*64+s][m] = (1/8) sum_k proto[s,hk]*W[hk,m]
        // wave = one mg group: proto row per-lane (L2-hot), W row wave-uniform.
        int h = bid >> 4, mr = bid & 15;
        int m0 = mr * 64;
        int s = tid & 63, mg = (tid >> 6) * 16;
        const float* prow  = &proto[(size_t)s * D_ + h * 64];
        const float* wbase = &W[(size_t)(h * 64) * D_ + m0 + mg];
        float acc[16] = {};
        for (int k = 0; k < 64; ++k) {
            float pv = prow[k];
            float4 w0 = *(const float4*)(wbase + (size_t)k * D_);
            float4 w1 = *(const float4*)(wbase + (size_t)k * D_ + 4);
            float4 w2 = *(const float4*)(wbase + (size_t)k * D_ + 8);
            float4 w3 = *(const float4*)(wbase + (size_t)k * D_ + 12);
            acc[0]  += pv * w0.x; acc[1]  += pv * w0.y;
            acc[2]  += pv * w0.z; acc[3]  += pv * w0.w;
            acc[4]  += pv * w1.x; acc[5]  += pv * w1.y;
            acc[6]  += pv * w1.z; acc[7]  += pv * w1.w;
            acc[8]  += pv * w2.x; acc[9]  += pv * w2.y;
            acc[10] += pv * w2.z; acc[11] += pv * w2.w;
            acc[12] += pv * w3.x; acc[13] += pv * w3.y;
            acc[14] += pv * w3.z; acc[15] += pv * w3.w;
        }
        unsigned short ob[16];
        #pragma unroll
        for (int i = 0; i < 16; ++i) ob[i] = f2bf(0.125f * acc[i]);
        unsigned short* dst = &Pb[(size_t)(h * 64 + s) * D_ + m0 + mg];
        *(uint4*)dst       = *(uint4*)&ob[0];
        *(uint4*)(dst + 8) = *(uint4*)&ob[8];
    } else {
        // ---- zero d_out (262144 floats) ----
        int bid3 = bid - 256;
        int off = bid3 * 1024 + tid * 4;
        *(float4*)&outp[off] = (float4){0.f, 0.f, 0.f, 0.f};
    }
}

// ---------------------------------------------------------------------------
// Kernel 2 (v4): pure bf16 MFMA GEMM -> raw scores in f16 (unchanged from R10:
// BK=64 single-buffered, both-sides T2 swizzle via pre-swizzled global src).
__global__ __launch_bounds__(256)
void k_gemm(const unsigned short* __restrict__ Ab,   // Hb [M_, D_] bf16
            const unsigned short* __restrict__ Bp,   // Pb [N_, D_] bf16
            _Float16* __restrict__ C) {              // scores [M_, N_] f16
    __shared__ unsigned short As[128 * 64];   // 16 KB
    __shared__ unsigned short Bs[128 * 64];   // 16 KB
    int tid = threadIdx.x;
    int bid = blockIdx.x;
    int wgid = (bid & 7) * 128 + (bid >> 3);
    int bm = wgid >> 3, bn = wgid & 7;
    int m0 = bm * 128, n0 = bn * 128;
    int l = tid & 63, wv = tid >> 6;
    int wr = wv >> 1, wc = wv & 1;
    int lr = l & 15, lk = l >> 4;

    int srow = tid >> 3;                  // 0..31
    int skgs = (tid & 7) ^ (srow & 7);    // pre-swizzled global 16B group
    const unsigned short* Ap = Ab + (size_t)(m0 + srow) * D_ + skgs * 8;
    const unsigned short* Bq = Bp + (size_t)(n0 + srow) * D_ + skgs * 8;

    f32x4 acc[4][4];
    #pragma unroll
    for (int i = 0; i < 4; ++i)
        #pragma unroll
        for (int j = 0; j < 4; ++j) acc[i][j] = (f32x4){0.f, 0.f, 0.f, 0.f};

    for (int k0 = 0; k0 < D_; k0 += 64) {
        __syncthreads();   // previous tile's MFMA reads complete
        #pragma unroll
        for (int i = 0; i < 4; ++i) {
            __builtin_amdgcn_global_load_lds(
                (const __attribute__((address_space(1))) void*)(Ap + (size_t)(i * 32) * D_ + k0),
                (__attribute__((address_space(3))) void*)(&As[tid * 8 + i * 2048]), 16, 0, 0);
            __builtin_amdgcn_global_load_lds(
                (const __attribute__((address_space(1))) void*)(Bq + (size_t)(i * 32) * D_ + k0),
                (__attribute__((address_space(3))) void*)(&Bs[tid * 8 + i * 2048]), 16, 0, 0);
        }
        __syncthreads();   // staging visible
        #pragma unroll
        for (int kk = 0; kk < 2; ++kk) {
            short8v af[4], bf[4];
            int gp = ((kk * 4 + lk) ^ (lr & 7)) * 8;
            #pragma unroll
            for (int m = 0; m < 4; ++m)
                af[m] = *(const short8v*)&As[(wr * 64 + m * 16 + lr) * 64 + gp];
            #pragma unroll
            for (int n = 0; n < 4; ++n)
                bf[n] = *(const short8v*)&Bs[(wc * 64 + n * 16 + lr) * 64 + gp];
            #pragma unroll
            for (int m = 0; m < 4; ++m)
                #pragma unroll
                for (int n = 0; n < 4; ++n)
                    acc[m][n] = __builtin_amdgcn_mfma_f32_16x16x32_bf16(
                        af[m], bf[n], acc[m][n], 0, 0, 0);
        }
    }

    int crow = m0 + wr * 64 + lk * 4;
    int ccol = n0 + wc * 64 + lr;
    #pragma unroll
    for (int m = 0; m < 4; ++m)
        #pragma unroll
        for (int n = 0; n < 4; ++n)
            #pragma unroll
            for (int j = 0; j < 4; ++j)
                C[(size_t)(crow + m * 16 + j) * N_ + ccol + n * 16] =
                    (_Float16)acc[m][n][j];
}

// ---------------------------------------------------------------------------
// Kernel 3 (v2): per-chunk g-products, vectorized (unchanged).
__global__ __launch_bounds__(256)
void k_cp(const _Float16* __restrict__ S, float* __restrict__ cp) {
    int bid = blockIdx.x;                 // 256
    int bh = bid >> 2, qt = bid & 3;
    int b = bh >> 4, h = bh & 15;
    int w = threadIdx.x >> 6, l = threadIdx.x & 63;
    int sg = (l & 7) * 8;
    for (int k = 0; k < 8; ++k) {
        int c = qt * 32 + w * 8 + k;
        int tb = c * CHUNK_;
        float pg[8] = {1.f, 1.f, 1.f, 1.f, 1.f, 1.f, 1.f, 1.f};
        #pragma unroll
        for (int i = 0; i < 4; ++i) {
            int t = tb + (l >> 3) + i * 8;
            f16x8 sv = *(const f16x8*)(S + (size_t)(b * T_ + t) * N_ + h * 64 + sg);
            float e[8]; float ps = 0.f;
            #pragma unroll
            for (int j = 0; j < 8; ++j) { e[j] = __expf((float)sv[j]); ps += e[j]; }
            ps += __shfl_xor(ps, 1);
            ps += __shfl_xor(ps, 2);
            ps += __shfl_xor(ps, 4);
            float inv = 1.f / ps;
            #pragma unroll
            for (int j = 0; j < 8; ++j) pg[j] *= 1.f - ALPHA_ * (e[j] * inv);
        }
        #pragma unroll
        for (int off = 8; off <= 32; off <<= 1)
            #pragma unroll
            for (int j = 0; j < 8; ++j) pg[j] *= __shfl_xor(pg[j], off);
        if ((l >> 3) == 0) {
            int base = (bh * NCH_ + c) * 64 + l * 8;
            *(float4*)&cp[base]     = (float4){pg[0], pg[1], pg[2], pg[3]};
            *(float4*)&cp[base + 4] = (float4){pg[4], pg[5], pg[6], pg[7]};
        }
    }
}

// ---------------------------------------------------------------------------
// Kernel 3b: PARALLEL cross-chunk exclusive suffix scan (unchanged).
__global__ __launch_bounds__(256)
void k_scan(const float* __restrict__ cp, float* __restrict__ csuf) {
    int bh = blockIdx.x;                  // 64
    __shared__ float buf[128][64];        // 32 KB
    __shared__ float segp[4][64];
    int tid = threadIdx.x;
    #pragma unroll
    for (int i = 0; i < 8; ++i) {
        int e = tid * 4 + i * 1024;
        int c = e >> 6, sc = e & 63;
        *(float4*)&buf[c][sc] = *(const float4*)&cp[(bh * NCH_ + c) * 64 + sc];
    }
    __syncthreads();
    int s = tid & 63, seg = tid >> 6;
    float pp = 1.f;
    #pragma unroll
    for (int r = 0; r < 32; ++r) pp *= buf[seg * 32 + r][s];
    segp[seg][s] = pp;
    __syncthreads();
    float suf = 1.f;
    if (seg <= 2) suf *= segp[3][s];
    if (seg <= 1) suf *= segp[2][s];
    if (seg == 0) suf *= segp[1][s];
    #pragma unroll
    for (int r = 31; r >= 0; --r) {
        int c = seg * 32 + r;
        csuf[(bh * NCH_ + c) * 64 + s] = suf;   // EXCLUSIVE suffix
        suf *= buf[c][s];
    }
}

// ---------------------------------------------------------------------------
// Kernel 4 (v5): softmax + weff walk + MFMA output accumulation.
// Reverted to R10 geometry (grid 1024, 4 iters — R11's 2048-grid doubled
// atomic contention and lost). Added T5 setprio around the MFMA cluster
// (4 independent blocks/CU = the attn-like regime where it measured +4-7%).
__global__ __launch_bounds__(256)
void k_out_mfma(const _Float16* __restrict__ S,       // raw scores
                const unsigned short* __restrict__ Hb,// bf16 H
                const float* __restrict__ csuf,
                float* __restrict__ out) {
    int bx = blockIdx.x;                  // 1024
    int cf = bx & 15, h = (bx >> 4) & 15, b = bx >> 8;
    __shared__ _Float16 ws16[64][72];           // softmaxed w
    __shared__ unsigned short tmp[64][72];      // staged Hb rows
    __shared__ float ppl[4][64];                // per-16-row g partial products
    __shared__ _Float16 wt[8 * 64 * 8];         // w_eff^T subtiled [tg][s][8]
    __shared__ _Float16 hd[8 * 64 * 8];         // H^T    subtiled [tg][d][8]
    int tid = threadIdx.x;
    int lr0 = tid >> 3, lc = (tid & 7) * 8;     // load role: rows lr0, lr0+32
    int s = tid & 63, q = tid >> 6;             // walk/transpose role
    int fr = s & 15, fk = s >> 4, wv = q;       // mfma role

    // T14: issue it=0 loads first so they overlap the csuf loads
    size_t rr0 = (size_t)(b * T_ + cf * 256 + lr0) * N_ + h * 64 + lc;
    f16x8  sv0 = *(const f16x8*)(S + rr0);
    f16x8  sv1 = *(const f16x8*)(S + rr0 + (size_t)32 * N_);
    short8v hv0 = *(const short8v*)(Hb + rr0);
    short8v hv1 = *(const short8v*)(Hb + rr0 + (size_t)32 * N_);

    // prologue: su[k] = exclusive suffix of chunk (cf*8 + k)
    int cbase = (b * NH_ + h) * NCH_ + cf * 8;
    float su[8];
    #pragma unroll
    for (int k = 0; k < 8; ++k)
        su[k] = csuf[(cbase + k) * 64 + s];

    f32x4 acc[4];
    #pragma unroll
    for (int n = 0; n < 4; ++n) acc[n] = (f32x4){0.f, 0.f, 0.f, 0.f};

    for (int it = 0; it < 4; ++it) {
        // softmax per row (8-lane group, no max-sub; |score| small)
        _Float16 w0[8], w1[8];
        {
            float e[8]; float ps = 0.f;
            #pragma unroll
            for (int j = 0; j < 8; ++j) { e[j] = __expf((float)sv0[j]); ps += e[j]; }
            ps += __shfl_xor(ps, 1); ps += __shfl_xor(ps, 2); ps += __shfl_xor(ps, 4);
            float inv = 1.f / ps;
            #pragma unroll
            for (int j = 0; j < 8; ++j) w0[j] = (_Float16)(e[j] * inv);
        }
        {
            float e[8]; float ps = 0.f;
            #pragma unroll
            for (int j = 0; j < 8; ++j) { e[j] = __expf((float)sv1[j]); ps += e[j]; }
            ps += __shfl_xor(ps, 1); ps += __shfl_xor(ps, 2); ps += __shfl_xor(ps, 4);
            float inv = 1.f / ps;
            #pragma unroll
            for (int j = 0; j < 8; ++j) w1[j] = (_Float16)(e[j] * inv);
        }
        // (barrier A removed: prior iter's barrier D already ordered all
        //  ws16/tmp readers; MFMA between D and here reads only wt/hd)
        *(f16x8*)&ws16[lr0][lc]      = *(f16x8*)w0;
        *(f16x8*)&ws16[lr0 + 32][lc] = *(f16x8*)w1;
        *(short8v*)&tmp[lr0][lc]      = hv0;
        *(short8v*)&tmp[lr0 + 32][lc] = hv1;
        __syncthreads();                  // B: ws16 + tmp visible
        // T14: issue next iteration's loads now (regs free, latency hidden)
        if (it < 3) {
            size_t rn = rr0 + (size_t)((it + 1) * 64) * N_;
            sv0 = *(const f16x8*)(S + rn);
            sv1 = *(const f16x8*)(S + rn + (size_t)32 * N_);
            hv0 = *(const short8v*)(Hb + rn);
            hv1 = *(const short8v*)(Hb + rn + (size_t)32 * N_);
        }
        // ppl: partial product of g over this thread's 16 rows
        {
            float pp = 1.f;
            #pragma unroll
            for (int r = 0; r < 16; ++r)
                pp *= 1.f - ALPHA_ * (float)ws16[q * 16 + r][s];
            ppl[q][s] = pp;
        }
        // transpose Hb: thread (q,s): tg = q and q+4, cvt bf16 -> f16
        #pragma unroll
        for (int x = 0; x < 2; ++x) {
            int tg = q + x * 4;
            _Float16 hreg[8];
            #pragma unroll
            for (int r = 0; r < 8; ++r) {
                unsigned short ub = tmp[tg * 8 + r][s];
                hreg[r] = (_Float16)__uint_as_float((unsigned)ub << 16);
            }
            *(f16x8*)&hd[(tg * 64 + s) * 8] = *(f16x8*)hreg;
        }
        __syncthreads();                  // C: ppl + hd visible
        // walk: rows q*16..q*16+15 backward; chunk split at q<2 | q>=2
        {
            float suf = (q >= 2) ? su[it * 2 + 1] : su[it * 2];
            if (q == 2) suf *= ppl[3][s];
            if (q == 0) suf *= ppl[1][s];
            _Float16 wr16[16];
            #pragma unroll
            for (int r = 15; r >= 0; --r) {
                float wv_ = (float)ws16[q * 16 + r][s];
                wr16[r] = (_Float16)(ALPHA_ * wv_ * suf);
                suf *= 1.f - ALPHA_ * wv_;
            }
            *(f16x8*)&wt[((2 * q)     * 64 + s) * 8] = *(f16x8*)&wr16[0];
            *(f16x8*)&wt[((2 * q + 1) * 64 + s) * 8] = *(f16x8*)&wr16[8];
        }
        __syncthreads();                  // D: wt visible
        // MFMA: wave wv -> s-block wv*16, all 64 d; K=64 = 2 k-steps
        __builtin_amdgcn_s_setprio(1);
        #pragma unroll
        for (int kk = 0; kk < 2; ++kk) {
            int tg = kk * 4 + fk;
            f16x8 af = *(const f16x8*)&wt[(tg * 64 + wv * 16 + fr) * 8];
            #pragma unroll
            for (int n = 0; n < 4; ++n) {
                f16x8 bf = *(const f16x8*)&hd[(tg * 64 + n * 16 + fr) * 8];
                acc[n] = __builtin_amdgcn_mfma_f32_16x16x32_f16(
                    af, bf, acc[n], 0, 0, 0);
            }
        }
        __builtin_amdgcn_s_setprio(0);
    }
    // D layout: row (s-dim) = fk*4 + j, col (d-dim) = fr
    #pragma unroll
    for (int n = 0; n < 4; ++n)
        #pragma unroll
        for (int j = 0; j < 4; ++j)
            atomicAdd(&out[((b * NS_ + wv * 16 + fk * 4 + j) * NH_ + h) * HD_
                           + n * 16 + fr],
                      acc[n][j]);
}

// ---------------------------------------------------------------------------
extern "C" void kernel_launch(void* const* d_in, const int* in_sizes, int n_in,
                              void* d_out, int out_size, void* d_ws, size_t ws_size,
                              hipStream_t stream) {
    const float* H     = (const float*)d_in[0];
    const float* proto = (const float*)d_in[1];
    const float* W     = (const float*)d_in[2];
    float* out = (float*)d_out;
    char*  ws  = (char*)d_ws;

    _Float16*       S  = (_Float16*)ws;                                  // 32 MB
    unsigned short* Hb = (unsigned short*)(ws + (size_t)M_ * N_ * 2);    // 32 MB
    unsigned short* Pb = (unsigned short*)(ws + (size_t)M_ * N_ * 2
                                              + (size_t)M_ * D_ * 2);    // 2 MB
    float* cp   = (float*)((char*)Pb + (size_t)N_ * D_ * 2);             // 2 MB
    float* csuf = cp + (size_t)B_ * NH_ * NCH_ * 64;                     // 2 MB

    k_prep      <<<2560,              256, 0, stream>>>(H, Hb, proto, W, Pb, out);
    k_gemm      <<<(M_/128)*(N_/128), 256, 0, stream>>>(Hb, Pb, S);
    k_cp        <<<256,               256, 0, stream>>>(S, cp);
    k_scan      <<<B_*NH_,            256, 0, stream>>>(cp, csuf);
    k_out_mfma  <<<B_*NH_*16,         256, 0, stream>>>(S, Hb, csuf, out);
}

// Round 13
// 110.173 us; speedup vs baseline: 1.0609x; 1.0039x over previous
//
#include <hip/hip_runtime.h>
#include <hip/hip_bf16.h>

// Problem constants
#define B_    4
#define T_    4096
#define D_    1024
#define NH_   16
#define NS_   64
#define HD_   64
#define ALPHA_ 0.1f
#define M_    (B_*T_)        // 16384 rows
#define N_    (NH_*NS_)      // 1024 cols (head*slot)
#define NCH_  128            // time chunks for the suffix scan
#define CHUNK_ (T_/NCH_)     // 32

typedef __attribute__((ext_vector_type(8))) short short8v;
typedef __attribute__((ext_vector_type(4))) float f32x4;
typedef _Float16 f16x8 __attribute__((ext_vector_type(8)));

__device__ inline unsigned short f2bf(float x) {
    unsigned u = __float_as_uint(x);
    unsigned r = u + 0x7FFF + ((u >> 16) & 1);   // RNE
    return (unsigned short)(r >> 16);
}

// ---------------------------------------------------------------------------
// Kernel 0 (v2): merged prep, zero LDS. blocks [0,256) = protoproj;
// [256,512) = zero d_out; [512,2560) = H fp32->bf16.
__global__ __launch_bounds__(256)
void k_prep(const float* __restrict__ H, unsigned short* __restrict__ Hb,
            const float* __restrict__ proto, const float* __restrict__ W,
            unsigned short* __restrict__ Pb, float* __restrict__ outp) {
    int bid = blockIdx.x;
    int tid = threadIdx.x;
    if (bid >= 512) {
        // ---- h2bf ----
        int idx = (bid - 512) * 256 + tid;            // unit = 8 floats
        const int stride = 2048 * 256;
        #pragma unroll
        for (int it = 0; it < 4; ++it) {
            int e = (idx + it * stride) * 8;
            float4 f0 = *(const float4*)&H[e];
            float4 f1 = *(const float4*)&H[e + 4];
            __hip_bfloat162 q0 = __float22bfloat162_rn(make_float2(f0.x, f0.y));
            __hip_bfloat162 q1 = __float22bfloat162_rn(make_float2(f0.z, f0.w));
            __hip_bfloat162 q2 = __float22bfloat162_rn(make_float2(f1.x, f1.y));
            __hip_bfloat162 q3 = __float22bfloat162_rn(make_float2(f1.z, f1.w));
            uint4 u = {*(unsigned*)&q0, *(unsigned*)&q1,
                       *(unsigned*)&q2, *(unsigned*)&q3};
            *(uint4*)&Hb[e] = u;
        }
    } else if (bid < 256) {
        // ---- protoproj (LDS-free)
        int h = bid >> 4, mr = bid & 15;
        int m0 = mr * 64;
        int s = tid & 63, mg = (tid >> 6) * 16;
        const float* prow  = &proto[(size_t)s * D_ + h * 64];
        const float* wbase = &W[(size_t)(h * 64) * D_ + m0 + mg];
        float acc[16] = {};
        for (int k = 0; k < 64; ++k) {
            float pv = prow[k];
            float4 w0 = *(const float4*)(wbase + (size_t)k * D_);
            float4 w1 = *(const float4*)(wbase + (size_t)k * D_ + 4);
            float4 w2 = *(const float4*)(wbase + (size_t)k * D_ + 8);
            float4 w3 = *(const float4*)(wbase + (size_t)k * D_ + 12);
            acc[0]  += pv * w0.x; acc[1]  += pv * w0.y;
            acc[2]  += pv * w0.z; acc[3]  += pv * w0.w;
            acc[4]  += pv * w1.x; acc[5]  += pv * w1.y;
            acc[6]  += pv * w1.z; acc[7]  += pv * w1.w;
            acc[8]  += pv * w2.x; acc[9]  += pv * w2.y;
            acc[10] += pv * w2.z; acc[11] += pv * w2.w;
            acc[12] += pv * w3.x; acc[13] += pv * w3.y;
            acc[14] += pv * w3.z; acc[15] += pv * w3.w;
        }
        unsigned short ob[16];
        #pragma unroll
        for (int i = 0; i < 16; ++i) ob[i] = f2bf(0.125f * acc[i]);
        unsigned short* dst = &Pb[(size_t)(h * 64 + s) * D_ + m0 + mg];
        *(uint4*)dst       = *(uint4*)&ob[0];
        *(uint4*)(dst + 8) = *(uint4*)&ob[8];
    } else {
        // ---- zero d_out ----
        int bid3 = bid - 256;
        int off = bid3 * 1024 + tid * 4;
        *(float4*)&outp[off] = (float4){0.f, 0.f, 0.f, 0.f};
    }
}

// ---------------------------------------------------------------------------
// Kernel 2 (v5): bf16 MFMA GEMM -> raw scores f16, COUNTED-VMCNT PIPELINE.
// 128x128 tile, BK=64, double-buffered (64 KB LDS). Per iter: issue tile
// t+1's 8 global_load_lds -> s_waitcnt vmcnt(8) (tile t home; t+1 stays in
// flight ACROSS both barriers) -> raw s_barrier -> ds_read+32 MFMA ->
// raw s_barrier (execution sync only; lgkmcnt before MFMA ordered reads).
// T2 both-sides swizzle unchanged (conflicts measured 0).
#define GFENCE  __builtin_amdgcn_sched_barrier(0)

__global__ __launch_bounds__(256)
void k_gemm(const unsigned short* __restrict__ Ab,   // Hb [M_, D_] bf16
            const unsigned short* __restrict__ Bp,   // Pb [N_, D_] bf16
            _Float16* __restrict__ C) {              // scores [M_, N_] f16
    __shared__ unsigned short As[2][128 * 64];   // 2 x 16 KB
    __shared__ unsigned short Bs[2][128 * 64];   // 2 x 16 KB
    int tid = threadIdx.x;
    int bid = blockIdx.x;
    int wgid = (bid & 7) * 128 + (bid >> 3);
    int bm = wgid >> 3, bn = wgid & 7;
    int m0 = bm * 128, n0 = bn * 128;
    int l = tid & 63, wv = tid >> 6;
    int wr = wv >> 1, wc = wv & 1;
    int lr = l & 15, lk = l >> 4;

    int srow = tid >> 3;                  // 0..31
    int skgs = (tid & 7) ^ (srow & 7);    // pre-swizzled global 16B group
    const unsigned short* Ap = Ab + (size_t)(m0 + srow) * D_ + skgs * 8;
    const unsigned short* Bq = Bp + (size_t)(n0 + srow) * D_ + skgs * 8;

    f32x4 acc[4][4];
    #pragma unroll
    for (int i = 0; i < 4; ++i)
        #pragma unroll
        for (int j = 0; j < 4; ++j) acc[i][j] = (f32x4){0.f, 0.f, 0.f, 0.f};

#define GSTAGE(BUF, K0)                                                         \
    _Pragma("unroll")                                                           \
    for (int i = 0; i < 4; ++i) {                                               \
        __builtin_amdgcn_global_load_lds(                                       \
            (const __attribute__((address_space(1))) void*)(Ap + (size_t)(i * 32) * D_ + (K0)), \
            (__attribute__((address_space(3))) void*)(&As[BUF][tid * 8 + i * 2048]), 16, 0, 0); \
        __builtin_amdgcn_global_load_lds(                                       \
            (const __attribute__((address_space(1))) void*)(Bq + (size_t)(i * 32) * D_ + (K0)), \
            (__attribute__((address_space(3))) void*)(&Bs[BUF][tid * 8 + i * 2048]), 16, 0, 0); \
    }

#define KSTEP(BUF)                                                              \
    _Pragma("unroll")                                                           \
    for (int kk = 0; kk < 2; ++kk) {                                            \
        short8v af[4], bf[4];                                                   \
        int gp = ((kk * 4 + lk) ^ (lr & 7)) * 8;                                \
        _Pragma("unroll")                                                       \
        for (int m = 0; m < 4; ++m)                                             \
            af[m] = *(const short8v*)&As[BUF][(wr * 64 + m * 16 + lr) * 64 + gp]; \
        _Pragma("unroll")                                                       \
        for (int n = 0; n < 4; ++n)                                             \
            bf[n] = *(const short8v*)&Bs[BUF][(wc * 64 + n * 16 + lr) * 64 + gp]; \
        _Pragma("unroll")                                                       \
        for (int m = 0; m < 4; ++m)                                             \
            _Pragma("unroll")                                                   \
            for (int n = 0; n < 4; ++n)                                         \
                acc[m][n] = __builtin_amdgcn_mfma_f32_16x16x32_bf16(            \
                    af[m], bf[n], acc[m][n], 0, 0, 0);                          \
    }

#define WAITC(N)  asm volatile("s_waitcnt vmcnt(" #N ")" ::: "memory")
#define BARRIER   GFENCE; __builtin_amdgcn_s_barrier(); GFENCE

    GSTAGE(0, 0)                          // prologue: tile 0 (8 loads)
    for (int t = 0; t < 14; t += 2) {
        GSTAGE(1, (t + 1) * 64)           // tile t+1 -> buf1 (8 in flight)
        WAITC(8);                         // tile t home; t+1 stays in flight
        BARRIER;
        KSTEP(0)                          // compute tile t from buf0
        BARRIER;                          // all waves done reading buf0
        GSTAGE(0, (t + 2) * 64)           // tile t+2 -> buf0
        WAITC(8);                         // tile t+1 home
        BARRIER;
        KSTEP(1)                          // compute tile t+1 from buf1
        BARRIER;
    }
    GSTAGE(1, 15 * 64)                    // tile 15 -> buf1
    WAITC(8);                             // tile 14 home
    BARRIER;
    KSTEP(0)                              // tile 14
    BARRIER;
    WAITC(0);                             // tile 15 home
    BARRIER;
    KSTEP(1)                              // tile 15
#undef GSTAGE
#undef KSTEP
#undef WAITC
#undef BARRIER

    int crow = m0 + wr * 64 + lk * 4;
    int ccol = n0 + wc * 64 + lr;
    #pragma unroll
    for (int m = 0; m < 4; ++m)
        #pragma unroll
        for (int n = 0; n < 4; ++n)
            #pragma unroll
            for (int j = 0; j < 4; ++j)
                C[(size_t)(crow + m * 16 + j) * N_ + ccol + n * 16] =
                    (_Float16)acc[m][n][j];
}

// ---------------------------------------------------------------------------
// Kernel 3 (v2): per-chunk g-products, vectorized (unchanged).
__global__ __launch_bounds__(256)
void k_cp(const _Float16* __restrict__ S, float* __restrict__ cp) {
    int bid = blockIdx.x;                 // 256
    int bh = bid >> 2, qt = bid & 3;
    int b = bh >> 4, h = bh & 15;
    int w = threadIdx.x >> 6, l = threadIdx.x & 63;
    int sg = (l & 7) * 8;
    for (int k = 0; k < 8; ++k) {
        int c = qt * 32 + w * 8 + k;
        int tb = c * CHUNK_;
        float pg[8] = {1.f, 1.f, 1.f, 1.f, 1.f, 1.f, 1.f, 1.f};
        #pragma unroll
        for (int i = 0; i < 4; ++i) {
            int t = tb + (l >> 3) + i * 8;
            f16x8 sv = *(const f16x8*)(S + (size_t)(b * T_ + t) * N_ + h * 64 + sg);
            float e[8]; float ps = 0.f;
            #pragma unroll
            for (int j = 0; j < 8; ++j) { e[j] = __expf((float)sv[j]); ps += e[j]; }
            ps += __shfl_xor(ps, 1);
            ps += __shfl_xor(ps, 2);
            ps += __shfl_xor(ps, 4);
            float inv = 1.f / ps;
            #pragma unroll
            for (int j = 0; j < 8; ++j) pg[j] *= 1.f - ALPHA_ * (e[j] * inv);
        }
        #pragma unroll
        for (int off = 8; off <= 32; off <<= 1)
            #pragma unroll
            for (int j = 0; j < 8; ++j) pg[j] *= __shfl_xor(pg[j], off);
        if ((l >> 3) == 0) {
            int base = (bh * NCH_ + c) * 64 + l * 8;
            *(float4*)&cp[base]     = (float4){pg[0], pg[1], pg[2], pg[3]};
            *(float4*)&cp[base + 4] = (float4){pg[4], pg[5], pg[6], pg[7]};
        }
    }
}

// ---------------------------------------------------------------------------
// Kernel 3b: PARALLEL cross-chunk exclusive suffix scan (unchanged).
__global__ __launch_bounds__(256)
void k_scan(const float* __restrict__ cp, float* __restrict__ csuf) {
    int bh = blockIdx.x;                  // 64
    __shared__ float buf[128][64];        // 32 KB
    __shared__ float segp[4][64];
    int tid = threadIdx.x;
    #pragma unroll
    for (int i = 0; i < 8; ++i) {
        int e = tid * 4 + i * 1024;
        int c = e >> 6, sc = e & 63;
        *(float4*)&buf[c][sc] = *(const float4*)&cp[(bh * NCH_ + c) * 64 + sc];
    }
    __syncthreads();
    int s = tid & 63, seg = tid >> 6;
    float pp = 1.f;
    #pragma unroll
    for (int r = 0; r < 32; ++r) pp *= buf[seg * 32 + r][s];
    segp[seg][s] = pp;
    __syncthreads();
    float suf = 1.f;
    if (seg <= 2) suf *= segp[3][s];
    if (seg <= 1) suf *= segp[2][s];
    if (seg == 0) suf *= segp[1][s];
    #pragma unroll
    for (int r = 31; r >= 0; --r) {
        int c = seg * 32 + r;
        csuf[(bh * NCH_ + c) * 64 + s] = suf;   // EXCLUSIVE suffix
        suf *= buf[c][s];
    }
}

// ---------------------------------------------------------------------------
// Kernel 4 (v6): softmax + weff walk + MFMA output accumulation.
// R10 geometry (grid 1024, 4 iters); setprio REMOVED (R12 post-mortem:
// barrier-lockstep waves = m190 regime where setprio is null-to-negative).
__global__ __launch_bounds__(256)
void k_out_mfma(const _Float16* __restrict__ S,       // raw scores
                const unsigned short* __restrict__ Hb,// bf16 H
                const float* __restrict__ csuf,
                float* __restrict__ out) {
    int bx = blockIdx.x;                  // 1024
    int cf = bx & 15, h = (bx >> 4) & 15, b = bx >> 8;
    __shared__ _Float16 ws16[64][72];           // softmaxed w
    __shared__ unsigned short tmp[64][72];      // staged Hb rows
    __shared__ float ppl[4][64];                // per-16-row g partial products
    __shared__ _Float16 wt[8 * 64 * 8];         // w_eff^T subtiled [tg][s][8]
    __shared__ _Float16 hd[8 * 64 * 8];         // H^T    subtiled [tg][d][8]
    int tid = threadIdx.x;
    int lr0 = tid >> 3, lc = (tid & 7) * 8;     // load role: rows lr0, lr0+32
    int s = tid & 63, q = tid >> 6;             // walk/transpose role
    int fr = s & 15, fk = s >> 4, wv = q;       // mfma role

    // T14: issue it=0 loads first so they overlap the csuf loads
    size_t rr0 = (size_t)(b * T_ + cf * 256 + lr0) * N_ + h * 64 + lc;
    f16x8  sv0 = *(const f16x8*)(S + rr0);
    f16x8  sv1 = *(const f16x8*)(S + rr0 + (size_t)32 * N_);
    short8v hv0 = *(const short8v*)(Hb + rr0);
    short8v hv1 = *(const short8v*)(Hb + rr0 + (size_t)32 * N_);

    // prologue: su[k] = exclusive suffix of chunk (cf*8 + k)
    int cbase = (b * NH_ + h) * NCH_ + cf * 8;
    float su[8];
    #pragma unroll
    for (int k = 0; k < 8; ++k)
        su[k] = csuf[(cbase + k) * 64 + s];

    f32x4 acc[4];
    #pragma unroll
    for (int n = 0; n < 4; ++n) acc[n] = (f32x4){0.f, 0.f, 0.f, 0.f};

    for (int it = 0; it < 4; ++it) {
        // softmax per row (8-lane group, no max-sub; |score| small)
        _Float16 w0[8], w1[8];
        {
            float e[8]; float ps = 0.f;
            #pragma unroll
            for (int j = 0; j < 8; ++j) { e[j] = __expf((float)sv0[j]); ps += e[j]; }
            ps += __shfl_xor(ps, 1); ps += __shfl_xor(ps, 2); ps += __shfl_xor(ps, 4);
            float inv = 1.f / ps;
            #pragma unroll
            for (int j = 0; j < 8; ++j) w0[j] = (_Float16)(e[j] * inv);
        }
        {
            float e[8]; float ps = 0.f;
            #pragma unroll
            for (int j = 0; j < 8; ++j) { e[j] = __expf((float)sv1[j]); ps += e[j]; }
            ps += __shfl_xor(ps, 1); ps += __shfl_xor(ps, 2); ps += __shfl_xor(ps, 4);
            float inv = 1.f / ps;
            #pragma unroll
            for (int j = 0; j < 8; ++j) w1[j] = (_Float16)(e[j] * inv);
        }
        // (barrier A removed: prior iter's barrier D already ordered all
        //  ws16/tmp readers; MFMA between D and here reads only wt/hd)
        *(f16x8*)&ws16[lr0][lc]      = *(f16x8*)w0;
        *(f16x8*)&ws16[lr0 + 32][lc] = *(f16x8*)w1;
        *(short8v*)&tmp[lr0][lc]      = hv0;
        *(short8v*)&tmp[lr0 + 32][lc] = hv1;
        __syncthreads();                  // B: ws16 + tmp visible
        // T14: issue next iteration's loads now (regs free, latency hidden)
        if (it < 3) {
            size_t rn = rr0 + (size_t)((it + 1) * 64) * N_;
            sv0 = *(const f16x8*)(S + rn);
            sv1 = *(const f16x8*)(S + rn + (size_t)32 * N_);
            hv0 = *(const short8v*)(Hb + rn);
            hv1 = *(const short8v*)(Hb + rn + (size_t)32 * N_);
        }
        // ppl: partial product of g over this thread's 16 rows
        {
            float pp = 1.f;
            #pragma unroll
            for (int r = 0; r < 16; ++r)
                pp *= 1.f - ALPHA_ * (float)ws16[q * 16 + r][s];
            ppl[q][s] = pp;
        }
        // transpose Hb: thread (q,s): tg = q and q+4, cvt bf16 -> f16
        #pragma unroll
        for (int x = 0; x < 2; ++x) {
            int tg = q + x * 4;
            _Float16 hreg[8];
            #pragma unroll
            for (int r = 0; r < 8; ++r) {
                unsigned short ub = tmp[tg * 8 + r][s];
                hreg[r] = (_Float16)__uint_as_float((unsigned)ub << 16);
            }
            *(f16x8*)&hd[(tg * 64 + s) * 8] = *(f16x8*)hreg;
        }
        __syncthreads();                  // C: ppl + hd visible
        // walk: rows q*16..q*16+15 backward; chunk split at q<2 | q>=2
        {
            float suf = (q >= 2) ? su[it * 2 + 1] : su[it * 2];
            if (q == 2) suf *= ppl[3][s];
            if (q == 0) suf *= ppl[1][s];
            _Float16 wr16[16];
            #pragma unroll
            for (int r = 15; r >= 0; --r) {
                float wv_ = (float)ws16[q * 16 + r][s];
                wr16[r] = (_Float16)(ALPHA_ * wv_ * suf);
                suf *= 1.f - ALPHA_ * wv_;
            }
            *(f16x8*)&wt[((2 * q)     * 64 + s) * 8] = *(f16x8*)&wr16[0];
            *(f16x8*)&wt[((2 * q + 1) * 64 + s) * 8] = *(f16x8*)&wr16[8];
        }
        __syncthreads();                  // D: wt visible
        // MFMA: wave wv -> s-block wv*16, all 64 d; K=64 = 2 k-steps
        #pragma unroll
        for (int kk = 0; kk < 2; ++kk) {
            int tg = kk * 4 + fk;
            f16x8 af = *(const f16x8*)&wt[(tg * 64 + wv * 16 + fr) * 8];
            #pragma unroll
            for (int n = 0; n < 4; ++n) {
                f16x8 bf = *(const f16x8*)&hd[(tg * 64 + n * 16 + fr) * 8];
                acc[n] = __builtin_amdgcn_mfma_f32_16x16x32_f16(
                    af, bf, acc[n], 0, 0, 0);
            }
        }
    }
    // D layout: row (s-dim) = fk*4 + j, col (d-dim) = fr
    #pragma unroll
    for (int n = 0; n < 4; ++n)
        #pragma unroll
        for (int j = 0; j < 4; ++j)
            atomicAdd(&out[((b * NS_ + wv * 16 + fk * 4 + j) * NH_ + h) * HD_
                           + n * 16 + fr],
                      acc[n][j]);
}

// ---------------------------------------------------------------------------
extern "C" void kernel_launch(void* const* d_in, const int* in_sizes, int n_in,
                              void* d_out, int out_size, void* d_ws, size_t ws_size,
                              hipStream_t stream) {
    const float* H     = (const float*)d_in[0];
    const float* proto = (const float*)d_in[1];
    const float* W     = (const float*)d_in[2];
    float* out = (float*)d_out;
    char*  ws  = (char*)d_ws;

    _Float16*       S  = (_Float16*)ws;                                  // 32 MB
    unsigned short* Hb = (unsigned short*)(ws + (size_t)M_ * N_ * 2);    // 32 MB
    unsigned short* Pb = (unsigned short*)(ws + (size_t)M_ * N_ * 2
                                              + (size_t)M_ * D_ * 2);    // 2 MB
    float* cp   = (float*)((char*)Pb + (size_t)N_ * D_ * 2);             // 2 MB
    float* csuf = cp + (size_t)B_ * NH_ * NCH_ * 64;                     // 2 MB

    k_prep      <<<2560,              256, 0, stream>>>(H, Hb, proto, W, Pb, out);
    k_gemm      <<<(M_/128)*(N_/128), 256, 0, stream>>>(Hb, Pb, S);
    k_cp        <<<256,               256, 0, stream>>>(S, cp);
    k_scan      <<<B_*NH_,            256, 0, stream>>>(cp, csuf);
    k_out_mfma  <<<B_*NH_*16,         256, 0, stream>>>(S, Hb, csuf, out);
}

// Round 14
// 103.511 us; speedup vs baseline: 1.1292x; 1.0644x over previous
//
#include <hip/hip_runtime.h>
#include <hip/hip_bf16.h>

// Problem constants
#define B_    4
#define T_    4096
#define D_    1024
#define NH_   16
#define NS_   64
#define HD_   64
#define ALPHA_ 0.1f
#define M_    (B_*T_)        // 16384 rows
#define N_    (NH_*NS_)      // 1024 cols (head*slot)
#define NCH_  128            // time chunks for the suffix scan
#define CHUNK_ (T_/NCH_)     // 32

typedef __attribute__((ext_vector_type(8))) short short8v;
typedef __attribute__((ext_vector_type(4))) float f32x4;
typedef _Float16 f16x8 __attribute__((ext_vector_type(8)));

__device__ inline unsigned short f2bf(float x) {
    unsigned u = __float_as_uint(x);
    unsigned r = u + 0x7FFF + ((u >> 16) & 1);   // RNE
    return (unsigned short)(r >> 16);
}

// ---------------------------------------------------------------------------
// Kernel 0: H fp32 -> bf16 (separate again — R13 post-mortem: merged prep
// cost ~2.5 µs vs separate).
__global__ __launch_bounds__(256)
void k_h2bf(const float* __restrict__ H, unsigned short* __restrict__ Hb) {
    int idx = blockIdx.x * 256 + threadIdx.x;         // unit = 8 floats
    const int stride = 2048 * 256;
    #pragma unroll
    for (int it = 0; it < 4; ++it) {
        int e = (idx + it * stride) * 8;
        float4 f0 = *(const float4*)&H[e];
        float4 f1 = *(const float4*)&H[e + 4];
        __hip_bfloat162 q0 = __float22bfloat162_rn(make_float2(f0.x, f0.y));
        __hip_bfloat162 q1 = __float22bfloat162_rn(make_float2(f0.z, f0.w));
        __hip_bfloat162 q2 = __float22bfloat162_rn(make_float2(f1.x, f1.y));
        __hip_bfloat162 q3 = __float22bfloat162_rn(make_float2(f1.z, f1.w));
        uint4 u = {*(unsigned*)&q0, *(unsigned*)&q1, *(unsigned*)&q2, *(unsigned*)&q3};
        *(uint4*)&Hb[e] = u;
    }
}

// ---------------------------------------------------------------------------
// Kernel 1: fold W_tok into prototypes, emit bf16 (R10 LDS version).
__global__ __launch_bounds__(256)
void k_protoproj(const float* __restrict__ proto,
                 const float* __restrict__ W,
                 unsigned short* __restrict__ Pb) {
    int bid = blockIdx.x;            // 256
    int h = bid >> 4, mr = bid & 15;
    int m0 = mr * 64;
    __shared__ float pl[64][68];
    __shared__ float Wl[64][68];
    int tid = threadIdx.x;
    int rr = tid >> 2, cg = (tid & 3) * 16;
    #pragma unroll
    for (int i = 0; i < 4; ++i)
        *(float4*)&pl[rr][cg + i * 4] =
            *(const float4*)&proto[rr * D_ + h * 64 + cg + i * 4];
    #pragma unroll
    for (int i = 0; i < 4; ++i)
        *(float4*)&Wl[rr][cg + i * 4] =
            *(const float4*)&W[(h * 64 + rr) * D_ + m0 + cg + i * 4];
    __syncthreads();
    int s = tid & 63, mg = (tid >> 6) * 16;
    float acc[16] = {};
    for (int k = 0; k < 64; ++k) {
        float pv = pl[s][k];
        #pragma unroll
        for (int i = 0; i < 16; ++i) acc[i] += pv * Wl[k][mg + i];
    }
    unsigned short ob[16];
    #pragma unroll
    for (int i = 0; i < 16; ++i) ob[i] = f2bf(0.125f * acc[i]);
    unsigned short* dst = &Pb[(size_t)(h * 64 + s) * D_ + m0 + mg];
    *(uint4*)dst       = *(uint4*)&ob[0];
    *(uint4*)(dst + 8) = *(uint4*)&ob[8];
}

// ---------------------------------------------------------------------------
// Kernel 2 (v6): bf16 MFMA GEMM, 256x256 TILE, counted-vmcnt pipeline.
// 512 threads = 8 waves (2M x 4N), per-wave 128x64 output (8x4 frags).
// BK=64, double-buffered dynamic LDS (128 KB, 1 block/CU). Same loop
// skeleton as R13 (GSTAGE -> WAITC(8) -> BARRIER -> KSTEP -> BARRIER),
// same both-sides swizzle (64-col rows, measured conflicts 0), same
// kk-then-mn accumulation order (bit-identical output).
// Staging traffic halves vs 128^2: 256 MB total (L2 floor ~7.5 us).
#define GFENCE  __builtin_amdgcn_sched_barrier(0)

__global__ __launch_bounds__(512, 2)
void k_gemm(const unsigned short* __restrict__ Ab,   // Hb [M_, D_] bf16
            const unsigned short* __restrict__ Bp,   // Pb [N_, D_] bf16
            _Float16* __restrict__ C) {              // scores [M_, N_] f16
    extern __shared__ unsigned short lds[];
    unsigned short* AsB[2] = {lds,         lds + 16384};   // 2 x 32 KB
    unsigned short* BsB[2] = {lds + 32768, lds + 49152};   // 2 x 32 KB
    int tid = threadIdx.x;                // 0..511
    int bid = blockIdx.x;                 // 0..255
    // XCD-bijective swizzle: 256 blocks, 8 XCDs -> 32 per XCD
    int wgid = (bid & 7) * 32 + (bid >> 3);
    int bm = wgid >> 2, bn = wgid & 3;    // 64 m-blocks, 4 n-blocks
    int m0 = bm * 256, n0 = bn * 256;
    int l = tid & 63, wv = tid >> 6;      // 8 waves
    int wr = wv >> 2, wc = wv & 3;        // 2M x 4N
    int lr = l & 15, lk = l >> 4;

    // staging: srow = tid>>3 (0..63), 16B group = tid&7, 4 issues x 64 rows
    int srow = tid >> 3;
    int skgs = (tid & 7) ^ (srow & 7);    // pre-swizzled global 16B group
    const unsigned short* Ap = Ab + (size_t)(m0 + srow) * D_ + skgs * 8;
    const unsigned short* Bq = Bp + (size_t)(n0 + srow) * D_ + skgs * 8;

    f32x4 acc[8][4];
    #pragma unroll
    for (int i = 0; i < 8; ++i)
        #pragma unroll
        for (int j = 0; j < 4; ++j) acc[i][j] = (f32x4){0.f, 0.f, 0.f, 0.f};

#define GSTAGE(BUF, K0)                                                         \
    _Pragma("unroll")                                                           \
    for (int i = 0; i < 4; ++i) {                                               \
        __builtin_amdgcn_global_load_lds(                                       \
            (const __attribute__((address_space(1))) void*)(Ap + (size_t)(i * 64) * D_ + (K0)), \
            (__attribute__((address_space(3))) void*)(&AsB[BUF][tid * 8 + i * 4096]), 16, 0, 0); \
        __builtin_amdgcn_global_load_lds(                                       \
            (const __attribute__((address_space(1))) void*)(Bq + (size_t)(i * 64) * D_ + (K0)), \
            (__attribute__((address_space(3))) void*)(&BsB[BUF][tid * 8 + i * 4096]), 16, 0, 0); \
    }

#define KSTEP(BUF)                                                              \
    {                                                                           \
        short8v bfr[4][2];                                                      \
        _Pragma("unroll")                                                       \
        for (int n = 0; n < 4; ++n)                                             \
            _Pragma("unroll")                                                   \
            for (int kk = 0; kk < 2; ++kk)                                      \
                bfr[n][kk] = *(const short8v*)&BsB[BUF][                        \
                    (wc * 64 + n * 16 + lr) * 64 + ((kk * 4 + lk) ^ (lr & 7)) * 8]; \
        _Pragma("unroll")                                                       \
        for (int m = 0; m < 8; ++m) {                                           \
            short8v af0 = *(const short8v*)&AsB[BUF][                           \
                (wr * 128 + m * 16 + lr) * 64 + ((lk) ^ (lr & 7)) * 8];         \
            short8v af1 = *(const short8v*)&AsB[BUF][                           \
                (wr * 128 + m * 16 + lr) * 64 + ((4 + lk) ^ (lr & 7)) * 8];     \
            _Pragma("unroll")                                                   \
            for (int n = 0; n < 4; ++n) {                                       \
                acc[m][n] = __builtin_amdgcn_mfma_f32_16x16x32_bf16(            \
                    af0, bfr[n][0], acc[m][n], 0, 0, 0);                        \
                acc[m][n] = __builtin_amdgcn_mfma_f32_16x16x32_bf16(            \
                    af1, bfr[n][1], acc[m][n], 0, 0, 0);                        \
            }                                                                   \
        }                                                                       \
    }

#define WAITC(N)  asm volatile("s_waitcnt vmcnt(" #N ")" ::: "memory")
#define BARRIER   GFENCE; __builtin_amdgcn_s_barrier(); GFENCE

    GSTAGE(0, 0)                          // prologue: tile 0 (8 loads)
    for (int t = 0; t < 14; t += 2) {
        GSTAGE(1, (t + 1) * 64)           // tile t+1 -> buf1 (8 in flight)
        WAITC(8);                         // tile t home; t+1 stays in flight
        BARRIER;
        KSTEP(0)                          // compute tile t from buf0
        BARRIER;                          // all waves done reading buf0
        GSTAGE(0, (t + 2) * 64)           // tile t+2 -> buf0
        WAITC(8);                         // tile t+1 home
        BARRIER;
        KSTEP(1)                          // compute tile t+1 from buf1
        BARRIER;
    }
    GSTAGE(1, 15 * 64)                    // tile 15 -> buf1
    WAITC(8);                             // tile 14 home
    BARRIER;
    KSTEP(0)                              // tile 14
    BARRIER;
    WAITC(0);                             // tile 15 home
    BARRIER;
    KSTEP(1)                              // tile 15
#undef GSTAGE
#undef KSTEP
#undef WAITC
#undef BARRIER

    // C/D layout: row = m0 + wr*128 + m*16 + lk*4 + j ; col = n0 + wc*64 + n*16 + lr
    int crow = m0 + wr * 128 + lk * 4;
    int ccol = n0 + wc * 64 + lr;
    #pragma unroll
    for (int m = 0; m < 8; ++m)
        #pragma unroll
        for (int n = 0; n < 4; ++n)
            #pragma unroll
            for (int j = 0; j < 4; ++j)
                C[(size_t)(crow + m * 16 + j) * N_ + ccol + n * 16] =
                    (_Float16)acc[m][n][j];
}

// ---------------------------------------------------------------------------
// Kernel 3: per-chunk g-products, vectorized (unchanged).
__global__ __launch_bounds__(256)
void k_cp(const _Float16* __restrict__ S, float* __restrict__ cp) {
    int bid = blockIdx.x;                 // 256
    int bh = bid >> 2, qt = bid & 3;
    int b = bh >> 4, h = bh & 15;
    int w = threadIdx.x >> 6, l = threadIdx.x & 63;
    int sg = (l & 7) * 8;
    for (int k = 0; k < 8; ++k) {
        int c = qt * 32 + w * 8 + k;
        int tb = c * CHUNK_;
        float pg[8] = {1.f, 1.f, 1.f, 1.f, 1.f, 1.f, 1.f, 1.f};
        #pragma unroll
        for (int i = 0; i < 4; ++i) {
            int t = tb + (l >> 3) + i * 8;
            f16x8 sv = *(const f16x8*)(S + (size_t)(b * T_ + t) * N_ + h * 64 + sg);
            float e[8]; float ps = 0.f;
            #pragma unroll
            for (int j = 0; j < 8; ++j) { e[j] = __expf((float)sv[j]); ps += e[j]; }
            ps += __shfl_xor(ps, 1);
            ps += __shfl_xor(ps, 2);
            ps += __shfl_xor(ps, 4);
            float inv = 1.f / ps;
            #pragma unroll
            for (int j = 0; j < 8; ++j) pg[j] *= 1.f - ALPHA_ * (e[j] * inv);
        }
        #pragma unroll
        for (int off = 8; off <= 32; off <<= 1)
            #pragma unroll
            for (int j = 0; j < 8; ++j) pg[j] *= __shfl_xor(pg[j], off);
        if ((l >> 3) == 0) {
            int base = (bh * NCH_ + c) * 64 + l * 8;
            *(float4*)&cp[base]     = (float4){pg[0], pg[1], pg[2], pg[3]};
            *(float4*)&cp[base + 4] = (float4){pg[4], pg[5], pg[6], pg[7]};
        }
    }
}

// ---------------------------------------------------------------------------
// Kernel 3b: PARALLEL cross-chunk exclusive suffix scan (unchanged).
__global__ __launch_bounds__(256)
void k_scan(const float* __restrict__ cp, float* __restrict__ csuf) {
    int bh = blockIdx.x;                  // 64
    __shared__ float buf[128][64];        // 32 KB
    __shared__ float segp[4][64];
    int tid = threadIdx.x;
    #pragma unroll
    for (int i = 0; i < 8; ++i) {
        int e = tid * 4 + i * 1024;
        int c = e >> 6, sc = e & 63;
        *(float4*)&buf[c][sc] = *(const float4*)&cp[(bh * NCH_ + c) * 64 + sc];
    }
    __syncthreads();
    int s = tid & 63, seg = tid >> 6;
    float pp = 1.f;
    #pragma unroll
    for (int r = 0; r < 32; ++r) pp *= buf[seg * 32 + r][s];
    segp[seg][s] = pp;
    __syncthreads();
    float suf = 1.f;
    if (seg <= 2) suf *= segp[3][s];
    if (seg <= 1) suf *= segp[2][s];
    if (seg == 0) suf *= segp[1][s];
    #pragma unroll
    for (int r = 31; r >= 0; --r) {
        int c = seg * 32 + r;
        csuf[(bh * NCH_ + c) * 64 + s] = suf;   // EXCLUSIVE suffix
        suf *= buf[c][s];
    }
}

// ---------------------------------------------------------------------------
// Kernel 4: softmax + weff walk + MFMA output accumulation (R13 version).
__global__ __launch_bounds__(256)
void k_out_mfma(const _Float16* __restrict__ S,       // raw scores
                const unsigned short* __restrict__ Hb,// bf16 H
                const float* __restrict__ csuf,
                float* __restrict__ out) {
    int bx = blockIdx.x;                  // 1024
    int cf = bx & 15, h = (bx >> 4) & 15, b = bx >> 8;
    __shared__ _Float16 ws16[64][72];           // softmaxed w
    __shared__ unsigned short tmp[64][72];      // staged Hb rows
    __shared__ float ppl[4][64];                // per-16-row g partial products
    __shared__ _Float16 wt[8 * 64 * 8];         // w_eff^T subtiled [tg][s][8]
    __shared__ _Float16 hd[8 * 64 * 8];         // H^T    subtiled [tg][d][8]
    int tid = threadIdx.x;
    int lr0 = tid >> 3, lc = (tid & 7) * 8;     // load role: rows lr0, lr0+32
    int s = tid & 63, q = tid >> 6;             // walk/transpose role
    int fr = s & 15, fk = s >> 4, wv = q;       // mfma role

    // T14: issue it=0 loads first so they overlap the csuf loads
    size_t rr0 = (size_t)(b * T_ + cf * 256 + lr0) * N_ + h * 64 + lc;
    f16x8  sv0 = *(const f16x8*)(S + rr0);
    f16x8  sv1 = *(const f16x8*)(S + rr0 + (size_t)32 * N_);
    short8v hv0 = *(const short8v*)(Hb + rr0);
    short8v hv1 = *(const short8v*)(Hb + rr0 + (size_t)32 * N_);

    // prologue: su[k] = exclusive suffix of chunk (cf*8 + k)
    int cbase = (b * NH_ + h) * NCH_ + cf * 8;
    float su[8];
    #pragma unroll
    for (int k = 0; k < 8; ++k)
        su[k] = csuf[(cbase + k) * 64 + s];

    f32x4 acc[4];
    #pragma unroll
    for (int n = 0; n < 4; ++n) acc[n] = (f32x4){0.f, 0.f, 0.f, 0.f};

    for (int it = 0; it < 4; ++it) {
        // softmax per row (8-lane group, no max-sub; |score| small)
        _Float16 w0[8], w1[8];
        {
            float e[8]; float ps = 0.f;
            #pragma unroll
            for (int j = 0; j < 8; ++j) { e[j] = __expf((float)sv0[j]); ps += e[j]; }
            ps += __shfl_xor(ps, 1); ps += __shfl_xor(ps, 2); ps += __shfl_xor(ps, 4);
            float inv = 1.f / ps;
            #pragma unroll
            for (int j = 0; j < 8; ++j) w0[j] = (_Float16)(e[j] * inv);
        }
        {
            float e[8]; float ps = 0.f;
            #pragma unroll
            for (int j = 0; j < 8; ++j) { e[j] = __expf((float)sv1[j]); ps += e[j]; }
            ps += __shfl_xor(ps, 1); ps += __shfl_xor(ps, 2); ps += __shfl_xor(ps, 4);
            float inv = 1.f / ps;
            #pragma unroll
            for (int j = 0; j < 8; ++j) w1[j] = (_Float16)(e[j] * inv);
        }
        // (barrier A removed: prior iter's barrier D already ordered all
        //  ws16/tmp readers; MFMA between D and here reads only wt/hd)
        *(f16x8*)&ws16[lr0][lc]      = *(f16x8*)w0;
        *(f16x8*)&ws16[lr0 + 32][lc] = *(f16x8*)w1;
        *(short8v*)&tmp[lr0][lc]      = hv0;
        *(short8v*)&tmp[lr0 + 32][lc] = hv1;
        __syncthreads();                  // B: ws16 + tmp visible
        // T14: issue next iteration's loads now (regs free, latency hidden)
        if (it < 3) {
            size_t rn = rr0 + (size_t)((it + 1) * 64) * N_;
            sv0 = *(const f16x8*)(S + rn);
            sv1 = *(const f16x8*)(S + rn + (size_t)32 * N_);
            hv0 = *(const short8v*)(Hb + rn);
            hv1 = *(const short8v*)(Hb + rn + (size_t)32 * N_);
        }
        // ppl: partial product of g over this thread's 16 rows
        {
            float pp = 1.f;
            #pragma unroll
            for (int r = 0; r < 16; ++r)
                pp *= 1.f - ALPHA_ * (float)ws16[q * 16 + r][s];
            ppl[q][s] = pp;
        }
        // transpose Hb: thread (q,s): tg = q and q+4, cvt bf16 -> f16
        #pragma unroll
        for (int x = 0; x < 2; ++x) {
            int tg = q + x * 4;
            _Float16 hreg[8];
            #pragma unroll
            for (int r = 0; r < 8; ++r) {
                unsigned short ub = tmp[tg * 8 + r][s];
                hreg[r] = (_Float16)__uint_as_float((unsigned)ub << 16);
            }
            *(f16x8*)&hd[(tg * 64 + s) * 8] = *(f16x8*)hreg;
        }
        __syncthreads();                  // C: ppl + hd visible
        // walk: rows q*16..q*16+15 backward; chunk split at q<2 | q>=2
        {
            float suf = (q >= 2) ? su[it * 2 + 1] : su[it * 2];
            if (q == 2) suf *= ppl[3][s];
            if (q == 0) suf *= ppl[1][s];
            _Float16 wr16[16];
            #pragma unroll
            for (int r = 15; r >= 0; --r) {
                float wv_ = (float)ws16[q * 16 + r][s];
                wr16[r] = (_Float16)(ALPHA_ * wv_ * suf);
                suf *= 1.f - ALPHA_ * wv_;
            }
            *(f16x8*)&wt[((2 * q)     * 64 + s) * 8] = *(f16x8*)&wr16[0];
            *(f16x8*)&wt[((2 * q + 1) * 64 + s) * 8] = *(f16x8*)&wr16[8];
        }
        __syncthreads();                  // D: wt visible
        // MFMA: wave wv -> s-block wv*16, all 64 d; K=64 = 2 k-steps
        #pragma unroll
        for (int kk = 0; kk < 2; ++kk) {
            int tg = kk * 4 + fk;
            f16x8 af = *(const f16x8*)&wt[(tg * 64 + wv * 16 + fr) * 8];
            #pragma unroll
            for (int n = 0; n < 4; ++n) {
                f16x8 bf = *(const f16x8*)&hd[(tg * 64 + n * 16 + fr) * 8];
                acc[n] = __builtin_amdgcn_mfma_f32_16x16x32_f16(
                    af, bf, acc[n], 0, 0, 0);
            }
        }
    }
    // D layout: row (s-dim) = fk*4 + j, col (d-dim) = fr
    #pragma unroll
    for (int n = 0; n < 4; ++n)
        #pragma unroll
        for (int j = 0; j < 4; ++j)
            atomicAdd(&out[((b * NS_ + wv * 16 + fk * 4 + j) * NH_ + h) * HD_
                           + n * 16 + fr],
                      acc[n][j]);
}

// ---------------------------------------------------------------------------
extern "C" void kernel_launch(void* const* d_in, const int* in_sizes, int n_in,
                              void* d_out, int out_size, void* d_ws, size_t ws_size,
                              hipStream_t stream) {
    const float* H     = (const float*)d_in[0];
    const float* proto = (const float*)d_in[1];
    const float* W     = (const float*)d_in[2];
    float* out = (float*)d_out;
    char*  ws  = (char*)d_ws;

    _Float16*       S  = (_Float16*)ws;                                  // 32 MB
    unsigned short* Hb = (unsigned short*)(ws + (size_t)M_ * N_ * 2);    // 32 MB
    unsigned short* Pb = (unsigned short*)(ws + (size_t)M_ * N_ * 2
                                              + (size_t)M_ * D_ * 2);    // 2 MB
    float* cp   = (float*)((char*)Pb + (size_t)N_ * D_ * 2);             // 2 MB
    float* csuf = cp + (size_t)B_ * NH_ * NCH_ * 64;                     // 2 MB

    // allow 128 KB dynamic LDS for the 256^2 GEMM (host-side, capture-safe)
    hipFuncSetAttribute((const void*)k_gemm,
                        hipFuncAttributeMaxDynamicSharedMemorySize, 131072);

    hipMemsetAsync(d_out, 0, (size_t)out_size * sizeof(float), stream);

    k_h2bf      <<<2048,      256, 0,      stream>>>(H, Hb);
    k_protoproj <<<256,       256, 0,      stream>>>(proto, W, Pb);
    k_gemm      <<<256,       512, 131072, stream>>>(Hb, Pb, S);
    k_cp        <<<256,       256, 0,      stream>>>(S, cp);
    k_scan      <<<B_*NH_,    256, 0,      stream>>>(cp, csuf);
    k_out_mfma  <<<B_*NH_*16, 256, 0,      stream>>>(S, Hb, csuf, out);
}